// Round 5
// baseline (40.927 us; speedup 1.0000x reference)
//
#include <hip/hip_runtime.h>

#define NSTEPS 10
#define D_IN   14400
#define KNN_K  25

// layer dims
#define L0D 7200
#define L1D 3600
#define L2D 1800
#define L3D 900
#define L4D 450

// 64-row groups per layer (ceil(dim/64)); 13 uint2 slots x 64 lanes per group
#define G0 113
#define G1 57
#define G2 29
#define G3 15
#define G4 8
#define SPG 832
#define O1 (G0*SPG)
#define O2 (O1 + G1*SPG)
#define O3 (O2 + G2*SPG)
#define O4 (O3 + G3*SPG)
#define OTOT (O4 + G4*SPG)     // 184704 uint2

#define NG    64               // batch groups of 4
#define PACKQ (D_IN/4)         // feature-quads per group
#define NPACK (NG * PACKQ)     // 230400

// round-to-nearest-even f32 -> bf16 bits
__device__ __forceinline__ unsigned bf16b(float x) {
    unsigned u = __float_as_uint(x);
    return (u + 0x7fffu + ((u >> 16) & 1u)) >> 16;
}

// one (idx,w) element against 4 packed batches: u = (bf16_w << 16) | idx
// act word = uint2{ b0|b1<<16, b2|b3<<16 }
__device__ __forceinline__ void gp4(unsigned u, const char* actb,
                                    float& a0, float& a1, float& a2, float& a3) {
    const uint2 av = *(const uint2*)(actb + 8u * (u & 0xffffu));   // ds_read_b64
    const float wf = __uint_as_float(u & 0xffff0000u);
    a0 = fmaf(__uint_as_float(av.x << 16),         wf, a0);
    a1 = fmaf(__uint_as_float(av.x & 0xffff0000u), wf, a1);
    a2 = fmaf(__uint_as_float(av.y << 16),         wf, a2);
    a3 = fmaf(__uint_as_float(av.y & 0xffff0000u), wf, a3);
}

// ---- prep: (A) lane-major SoA weight tiles, (B) pack input slice 4-batch bf16 ----
__global__ void prep_kernel(const int* __restrict__ k0, const float* __restrict__ w0,
                            const int* __restrict__ k1, const float* __restrict__ w1,
                            const int* __restrict__ k2, const float* __restrict__ w2,
                            const int* __restrict__ k3, const float* __restrict__ w3,
                            const int* __restrict__ k4, const float* __restrict__ w4,
                            const float* __restrict__ input,
                            uint2* __restrict__ tile, uint2* __restrict__ xpk)
{
    int s = blockIdx.x * 256 + threadIdx.x;
    if (s < OTOT) {
        const int* kp; const float* wp; int dim, t;
        if      (s < O1) { kp = k0; wp = w0; dim = L0D; t = s;      }
        else if (s < O2) { kp = k1; wp = w1; dim = L1D; t = s - O1; }
        else if (s < O3) { kp = k2; wp = w2; dim = L2D; t = s - O2; }
        else if (s < O4) { kp = k3; wp = w3; dim = L3D; t = s - O3; }
        else             { kp = k4; wp = w4; dim = L4D; t = s - O4; }
        int g    = t / SPG;
        int rem  = t - g * SPG;
        int j    = rem >> 6;          // 0..12
        int lane = rem & 63;
        int r    = g * 64 + lane;
        unsigned vx = 0, vy = 0;
        if (r < dim) {
            int e0 = 2 * j, e1 = 2 * j + 1;
            if (e0 < KNN_K) vx = (bf16b(wp[r * KNN_K + e0]) << 16) | (unsigned)kp[r * KNN_K + e0];
            if (e1 < KNN_K) vy = (bf16b(wp[r * KNN_K + e1]) << 16) | (unsigned)kp[r * KNN_K + e1];
        }
        tile[s] = make_uint2(vx, vy);
        return;
    }
    int t = s - OTOT;
    if (t < NPACK) {
        int g = t / PACKQ;
        int c = t - g * PACKQ;         // feature quad: features 4c..4c+3
        float4 r[4];
#pragma unroll
        for (int b = 0; b < 4; ++b)
            r[b] = *(const float4*)(input + ((size_t)(4 * g + b) * NSTEPS + NSTEPS - 1) * D_IN + 4 * c);
        uint4 lo, hi;
        lo.x = bf16b(r[0].x) | (bf16b(r[1].x) << 16);
        lo.y = bf16b(r[2].x) | (bf16b(r[3].x) << 16);
        lo.z = bf16b(r[0].y) | (bf16b(r[1].y) << 16);
        lo.w = bf16b(r[2].y) | (bf16b(r[3].y) << 16);
        hi.x = bf16b(r[0].z) | (bf16b(r[1].z) << 16);
        hi.y = bf16b(r[2].z) | (bf16b(r[3].z) << 16);
        hi.z = bf16b(r[0].w) | (bf16b(r[1].w) << 16);
        hi.w = bf16b(r[2].w) | (bf16b(r[3].w) << 16);
        uint4* dst = (uint4*)(xpk + ((size_t)g * D_IN + 4 * c));
        dst[0] = lo;
        dst[1] = hi;
    }
}

// ---- generic gather layer: stage PREV 4-batch words to LDS, compute DIM/NSPLIT rows ----
template<int PREV, int DIM, int NSPLIT, int BLK>
__device__ __forceinline__ void glayer(const uint2* __restrict__ xin_g,
                                       uint2* __restrict__ yout_g,
                                       const uint2* __restrict__ tile,
                                       const float* __restrict__ bias,
                                       uint2* act, int tid, int q)
{
    const uint4* src = (const uint4*)xin_g;
    for (int i = tid; i < PREV / 2; i += BLK)
        *(uint4*)(act + 2 * i) = src[i];
    __syncthreads();
    const char* actb = (const char*)act;
    constexpr int ROWS = DIM / NSPLIT;
    const int r0 = q * ROWS;
#pragma unroll
    for (int i = 0; i < (ROWS + BLK - 1) / BLK; ++i) {
        int rr = tid + i * BLK;
        if (rr < ROWS) {
            int r = r0 + rr;
            const uint2* tp = tile + (size_t)(r >> 6) * SPG + (r & 63);
            const float bv = bias[r];
            float x0 = bv, x1 = bv, x2 = bv, x3 = bv;   // chain A
            float z0 = 0, z1 = 0, z2 = 0, z3 = 0;       // chain B
#pragma unroll
            for (int j = 0; j < 13; ++j) {
                uint2 u = tp[j * 64];                    // coalesced 512B/wave
                gp4(u.x, actb, x0, x1, x2, x3);
                gp4(u.y, actb, z0, z1, z2, z3);
            }
            x0 += z0; x1 += z1; x2 += z2; x3 += z3;
            yout_g[r] = make_uint2(bf16b(x0) | (bf16b(x1) << 16),
                                   bf16b(x2) | (bf16b(x3) << 16));
        }
    }
}

// ---- layer kernels: grid = NG groups x NSPLIT neuron-splits ----
__global__ __launch_bounds__(1024, 1)
void lcn_l0(const uint2* __restrict__ xpk, const uint2* __restrict__ tile,
            const float* __restrict__ bias0, uint2* __restrict__ y0)
{
    __shared__ uint2 act[D_IN];            // 115.2 KB
    const int g = blockIdx.x >> 2, q = blockIdx.x & 3;
    glayer<D_IN, L0D, 4, 1024>(xpk + (size_t)g * D_IN, y0 + (size_t)g * L0D,
                               tile, bias0, act, threadIdx.x, q);
}

__global__ __launch_bounds__(1024, 2)
void lcn_l1(const uint2* __restrict__ y0, const uint2* __restrict__ tile,
            const float* __restrict__ bias1, uint2* __restrict__ y1)
{
    __shared__ uint2 act[L0D];             // 57.6 KB
    const int g = blockIdx.x >> 2, q = blockIdx.x & 3;
    glayer<L0D, L1D, 4, 1024>(y0 + (size_t)g * L0D, y1 + (size_t)g * L1D,
                              tile + O1, bias1, act, threadIdx.x, q);
}

__global__ __launch_bounds__(512, 4)
void lcn_l2(const uint2* __restrict__ y1, const uint2* __restrict__ tile,
            const float* __restrict__ bias2, uint2* __restrict__ y2)
{
    __shared__ uint2 act[L1D];             // 28.8 KB
    const int g = blockIdx.x >> 2, q = blockIdx.x & 3;
    glayer<L1D, L2D, 4, 512>(y1 + (size_t)g * L1D, y2 + (size_t)g * L2D,
                             tile + O2, bias2, act, threadIdx.x, q);
}

// ---- layers 3,4 + fc head: one block per group ----
__global__ __launch_bounds__(1024, 2)
void lcn_rest(const uint2* __restrict__ y2, const uint2* __restrict__ tile,
              const float* __restrict__ bias3, const float* __restrict__ bias4,
              const float* __restrict__ fc_w,  const float* __restrict__ fc_b,
              float* __restrict__ out)
{
    __shared__ uint2 act[L2D + L3D + L4D]; // 25.2 KB
    const int tid = threadIdx.x;
    const int g   = blockIdx.x;

    const uint4* src = (const uint4*)(y2 + (size_t)g * L2D);
    if (tid < L2D / 2) *(uint4*)(act + 2 * tid) = src[tid];
    __syncthreads();

    // L3: 900 rows from act[0:1800) -> act[1800:2700)
    {
        const char* actb = (const char*)act;
        if (tid < L3D) {
            const int r = tid;
            const uint2* tp = tile + O3 + (size_t)(r >> 6) * SPG + (r & 63);
            const float bv = bias3[r];
            float x0 = bv, x1 = bv, x2 = bv, x3 = bv, z0 = 0, z1 = 0, z2 = 0, z3 = 0;
#pragma unroll
            for (int j = 0; j < 13; ++j) {
                uint2 u = tp[j * 64];
                gp4(u.x, actb, x0, x1, x2, x3);
                gp4(u.y, actb, z0, z1, z2, z3);
            }
            x0 += z0; x1 += z1; x2 += z2; x3 += z3;
            act[L2D + r] = make_uint2(bf16b(x0) | (bf16b(x1) << 16),
                                      bf16b(x2) | (bf16b(x3) << 16));
        }
    }
    __syncthreads();

    // L4: 450 rows from act[1800:2700) -> act[2700:3150)
    {
        const char* actb = (const char*)(act + L2D);
        if (tid < L4D) {
            const int r = tid;
            const uint2* tp = tile + O4 + (size_t)(r >> 6) * SPG + (r & 63);
            const float bv = bias4[r];
            float x0 = bv, x1 = bv, x2 = bv, x3 = bv, z0 = 0, z1 = 0, z2 = 0, z3 = 0;
#pragma unroll
            for (int j = 0; j < 13; ++j) {
                uint2 u = tp[j * 64];
                gp4(u.x, actb, x0, x1, x2, x3);
                gp4(u.y, actb, z0, z1, z2, z3);
            }
            x0 += z0; x1 += z1; x2 += z2; x3 += z3;
            act[L2D + L3D + r] = make_uint2(bf16b(x0) | (bf16b(x1) << 16),
                                            bf16b(x2) | (bf16b(x3) << 16));
        }
    }
    __syncthreads();

    // FC: 8 waves -> (out o, batch j)
    const uint2* C = act + L2D + L3D;
    const int wv = tid >> 6, lane = tid & 63;
    if (wv < 8) {
        const int o = wv >> 2, j = wv & 3;
        float s = 0.f;
#pragma unroll
        for (int it = 0; it < 8; ++it) {
            int r = lane + it * 64;
            if (r < L4D) {
                uint2 av = C[r];
                unsigned wsel = (j >> 1) ? av.y : av.x;
                unsigned h = (j & 1) ? (wsel & 0xffff0000u) : (wsel << 16);
                s += __uint_as_float(h) * fc_w[o * L4D + r];
            }
        }
#pragma unroll
        for (int off = 32; off > 0; off >>= 1) s += __shfl_xor(s, off);
        if (lane == 0) out[(4 * g + j) * 2 + o] = s + fc_b[o];
    }
}

extern "C" void kernel_launch(void* const* d_in, const int* in_sizes, int n_in,
                              void* d_out, int out_size, void* d_ws, size_t ws_size,
                              hipStream_t stream) {
    const float* input = (const float*)d_in[0];
    const int*   knn[5];
    const float* w[5];
    const float* bias[5];
    for (int i = 0; i < 5; ++i) {
        knn[i]  = (const int*)  d_in[1 + 3 * i];
        w[i]    = (const float*)d_in[2 + 3 * i];
        bias[i] = (const float*)d_in[3 + 3 * i];
    }
    const float* fc_w = (const float*)d_in[16];
    const float* fc_b = (const float*)d_in[17];
    float* out = (float*)d_out;

    // ws layout (all 16B-aligned)
    char* base = (char*)d_ws;
    uint2* tile = (uint2*)base;                                   // 1.478 MB
    uint2* xpk  = (uint2*)(base + (size_t)OTOT * 8);              // 7.373 MB
    uint2* y0   = (uint2*)((char*)xpk + (size_t)NG * D_IN * 8);   // 3.686 MB
    uint2* y1   = (uint2*)((char*)y0  + (size_t)NG * L0D * 8);    // 1.843 MB
    uint2* y2   = (uint2*)((char*)y1  + (size_t)NG * L1D * 8);    // 0.922 MB

    const int nprep = OTOT + NPACK;
    prep_kernel<<<(nprep + 255) / 256, 256, 0, stream>>>(
        knn[0], w[0], knn[1], w[1], knn[2], w[2], knn[3], w[3], knn[4], w[4],
        input, tile, xpk);

    lcn_l0<<<NG * 4, 1024, 0, stream>>>(xpk, tile, bias[0], y0);
    lcn_l1<<<NG * 4, 1024, 0, stream>>>(y0, tile, bias[1], y1);
    lcn_l2<<<NG * 4, 512, 0, stream>>>(y1, tile, bias[2], y2);
    lcn_rest<<<NG, 1024, 0, stream>>>(y2, tile, bias[3], bias[4], fc_w, fc_b, out);
}